// Round 1
// baseline (478.722 us; speedup 1.0000x reference)
//
#include <hip/hip_runtime.h>
#include <hip/hip_bf16.h>

#define B 8
#define N 2048
#define FIN 10
#define D 128
#define TR 8     // rows per block in k_proj
#define TI 32    // rows per block in k_attn
#define JC 256   // j-chunk in k_attn

#define ALPHA 0.02f

__device__ __forceinline__ float lrelu(float x) { return x >= 0.f ? x : ALPHA * x; }

__device__ __forceinline__ unsigned enc_key(float v) {
    unsigned b = __float_as_uint(v);
    return (b & 0x80000000u) ? ~b : (b | 0x80000000u);
}
__device__ __forceinline__ float dec_key(unsigned k) {
    unsigned b = (k & 0x80000000u) ? (k & 0x7fffffffu) : ~k;
    return __uint_as_float(b);
}

// ---------------------------------------------------------------------------
// Kernel 1: x = lrelu(LN(h @ W1^T + b1)); Wh = x @ Wg^T + bg; e1 = Wh.a1; e2 = Wh.a2
// One block = TR=8 consecutive rows (global row index over B*N). 256 threads.
// ---------------------------------------------------------------------------
__global__ __launch_bounds__(256) void k_proj(
    const float* __restrict__ h, const float* __restrict__ W1, const float* __restrict__ b1,
    const float* __restrict__ Wg, const float* __restrict__ bg,
    const float* __restrict__ a1, const float* __restrict__ a2,
    float* __restrict__ Wh, float* __restrict__ e1g, float* __restrict__ e2g)
{
    __shared__ float W1_lds[D * FIN];      // 5 KB
    __shared__ float h_lds[TR * FIN];      // 320 B
    __shared__ float x_lds[TR][D];         // 4 KB
    __shared__ float whp[TR][D];           // 4 KB (half-1 partials)
    __shared__ float wh_lds[TR][D];        // 4 KB
    __shared__ float red[4][2];

    const int t = threadIdx.x;
    const int r0 = blockIdx.x * TR;        // global row base

    for (int idx = t; idx < D * FIN; idx += 256) W1_lds[idx] = W1[idx];
    if (t < TR * FIN) h_lds[t] = h[(size_t)r0 * FIN + t];
    __syncthreads();

    const int d = t & 127;
    const int hgroup = t >> 7;             // 0/1

    // ---- phase 1: fc1 + layernorm + lrelu, two rows at a time ----
    for (int rr2 = 0; rr2 < 4; rr2++) {
        const int rr = rr2 * 2 + hgroup;
        float s = b1[d];
        #pragma unroll
        for (int k = 0; k < FIN; k++) s += h_lds[rr * FIN + k] * W1_lds[d * FIN + k];

        float v = s, v2 = s * s;
        #pragma unroll
        for (int m = 1; m <= 32; m <<= 1) { v += __shfl_xor(v, m); v2 += __shfl_xor(v2, m); }
        const int wid = t >> 6;
        if ((t & 63) == 0) { red[wid][0] = v; red[wid][1] = v2; }
        __syncthreads();
        float sum   = red[hgroup * 2][0] + red[hgroup * 2 + 1][0];
        float sumsq = red[hgroup * 2][1] + red[hgroup * 2 + 1][1];
        float mean = sum * (1.f / D);
        float var  = sumsq * (1.f / D) - mean * mean;
        float xv = (s - mean) * rsqrtf(var + 1e-5f);
        x_lds[rr][d] = lrelu(xv);
        __syncthreads();
    }

    // ---- phase 2: Wh = x @ Wg^T + bg (halves split the k-range) ----
    float ws[TR];
    #pragma unroll
    for (int rr = 0; rr < TR; rr++) ws[rr] = 0.f;
    const int kbase = hgroup * 64;
    for (int k = 0; k < 64; k += 4) {
        float4 g = *(const float4*)&Wg[(size_t)d * D + kbase + k];
        #pragma unroll
        for (int rr = 0; rr < TR; rr++) {
            ws[rr] += x_lds[rr][kbase + k + 0] * g.x + x_lds[rr][kbase + k + 1] * g.y
                    + x_lds[rr][kbase + k + 2] * g.z + x_lds[rr][kbase + k + 3] * g.w;
        }
    }
    if (hgroup == 1) {
        #pragma unroll
        for (int rr = 0; rr < TR; rr++) whp[rr][d] = ws[rr];
    }
    __syncthreads();
    if (hgroup == 0) {
        float bgd = bg[d];
        #pragma unroll
        for (int rr = 0; rr < TR; rr++) {
            float tot = ws[rr] + whp[rr][d] + bgd;
            wh_lds[rr][d] = tot;
            Wh[(size_t)(r0 + rr) * D + d] = tot;
        }
    }
    __syncthreads();

    // ---- phase 3: e1/e2 reductions (32 lanes per row) ----
    const int row = t >> 5;                // 0..7
    const int q = t & 31;
    float s1 = 0.f, s2 = 0.f;
    #pragma unroll
    for (int m = 0; m < 4; m++) {
        int dd = q + 32 * m;
        float w = wh_lds[row][dd];
        s1 += w * a1[dd];
        s2 += w * a2[dd];
    }
    #pragma unroll
    for (int m = 1; m <= 16; m <<= 1) { s1 += __shfl_xor(s1, m); s2 += __shfl_xor(s2, m); }
    if (q == 0) {
        e1g[r0 + row] = s1;
        e2g[r0 + row] = s2;
    }
}

// ---------------------------------------------------------------------------
// Kernel 2: fused attention: p = adj ? exp(lrelu(e1_i+e2_j)) : 0 ;
//           hp_i = (sum_j p_ij Wh_j) / (sum_j p_ij); LN; lrelu; max-pool.
// Grid (N/TI, B), 256 threads. Thread = (d = t&127, ig = t>>7), 16 rows each.
// ---------------------------------------------------------------------------
__global__ __launch_bounds__(256) void k_attn(
    const int* __restrict__ adj, const float* __restrict__ Wh,
    const float* __restrict__ e1g, const float* __restrict__ e2g,
    unsigned* __restrict__ pooled)
{
    __shared__ float e2_lds[N];            // 8 KB
    __shared__ float e1_lds[TI];
    __shared__ float l_lds[TI];
    __shared__ float p_lds[TI][JC];        // 32 KB  (aliased as o_lds later)
    __shared__ float stats[TI][2];
    __shared__ float maxbuf[2][D];         // 1 KB

    const int t = threadIdx.x;
    const int b = blockIdx.y;
    const int i0 = blockIdx.x * TI;
    const int d = t & 127;
    const int ig = t >> 7;

    for (int idx = t; idx < N; idx += 256) e2_lds[idx] = e2g[b * N + idx];
    if (t < TI) { e1_lds[t] = e1g[b * N + i0 + t]; l_lds[t] = 0.f; }

    float acc[16];
    #pragma unroll
    for (int r = 0; r < 16; r++) acc[r] = 0.f;

    const float* WhB = Wh + (size_t)b * N * D;

    for (int jc = 0; jc < N / JC; jc++) {
        const int j0 = jc * JC;
        __syncthreads();   // prev chunk's p reads done; e2/e1/l init visible (iter 0)

        // phase A: p tile
        #pragma unroll 4
        for (int ii = 0; ii < TI; ii++) {
            int a = adj[((size_t)b * N + (i0 + ii)) * N + j0 + t];
            float e = lrelu(e1_lds[ii] + e2_lds[j0 + t]);
            p_lds[ii][t] = a ? __expf(e) : 0.f;
        }
        __syncthreads();

        // mini-phase: accumulate l per row (8 lanes per row)
        {
            const int rowq = t >> 3;       // 0..31
            const int q = t & 7;
            float s = 0.f;
            #pragma unroll
            for (int k = 0; k < JC / 8; k++) s += p_lds[rowq][q + 8 * k];
            #pragma unroll
            for (int m = 1; m <= 4; m <<= 1) s += __shfl_xor(s, m);
            if (q == 0) l_lds[rowq] += s;
        }

        // phase B: o += p * Wh  (p reads are wave-uniform -> LDS broadcast)
        const float* whj = WhB + (size_t)j0 * D + d;
        for (int jg = 0; jg < JC / 4; jg++) {
            float w0 = whj[(jg * 4 + 0) * D];
            float w1 = whj[(jg * 4 + 1) * D];
            float w2 = whj[(jg * 4 + 2) * D];
            float w3 = whj[(jg * 4 + 3) * D];
            #pragma unroll
            for (int r = 0; r < 16; r++) {
                int ii = ig * 16 + r;
                float4 p4 = *(const float4*)&p_lds[ii][jg * 4];
                acc[r] += p4.x * w0 + p4.y * w1 + p4.z * w2 + p4.w * w3;
            }
        }
    }
    __syncthreads();

    // epilogue: hp = o/l -> LDS (alias p_lds), LN stats, lrelu, max-pool
    float* o_base = &p_lds[0][0];          // [TI][132] view, 4224 floats <= 8192
    #pragma unroll
    for (int r = 0; r < 16; r++) {
        int ii = ig * 16 + r;
        o_base[ii * 132 + d] = acc[r] / l_lds[ii];
    }
    __syncthreads();
    {
        const int row = t >> 3;            // 0..31
        const int q = t & 7;
        float sm = 0.f, sq = 0.f;
        #pragma unroll
        for (int k = 0; k < D / 8; k++) {
            float v = o_base[row * 132 + q + 8 * k];
            sm += v; sq += v * v;
        }
        #pragma unroll
        for (int m = 1; m <= 4; m <<= 1) { sm += __shfl_xor(sm, m); sq += __shfl_xor(sq, m); }
        if (q == 0) { stats[row][0] = sm; stats[row][1] = sq; }
    }
    __syncthreads();
    float localmax = -1e30f;
    #pragma unroll
    for (int r = 0; r < 16; r++) {
        int ii = ig * 16 + r;
        float mean = stats[ii][0] * (1.f / D);
        float var  = stats[ii][1] * (1.f / D) - mean * mean;
        float v = (o_base[ii * 132 + d] - mean) * rsqrtf(var + 1e-5f);
        localmax = fmaxf(localmax, lrelu(v));
    }
    maxbuf[ig][d] = localmax;
    __syncthreads();
    if (ig == 0) {
        float mx = fmaxf(maxbuf[0][d], maxbuf[1][d]);
        atomicMax(&pooled[b * D + d], enc_key(mx));
    }
}

// ---------------------------------------------------------------------------
// Kernel 3: out = log_softmax(pooled @ W2^T + b2). 1 block, 256 thr (32/batch).
// ---------------------------------------------------------------------------
__global__ __launch_bounds__(256) void k_final(
    const unsigned* __restrict__ pooled, const float* __restrict__ W2,
    const float* __restrict__ b2, float* __restrict__ out)
{
    const int t = threadIdx.x;
    const int b = t >> 5;
    const int q = t & 31;
    float s0 = 0.f, s1 = 0.f;
    #pragma unroll
    for (int m = 0; m < 4; m++) {
        int dd = q + 32 * m;
        float v = dec_key(pooled[b * D + dd]);
        s0 += v * W2[dd];
        s1 += v * W2[D + dd];
    }
    #pragma unroll
    for (int m = 1; m <= 16; m <<= 1) { s0 += __shfl_xor(s0, m); s1 += __shfl_xor(s1, m); }
    if (q == 0) {
        float o0 = s0 + b2[0], o1 = s1 + b2[1];
        float mx = fmaxf(o0, o1);
        float ls = logf(__expf(o0 - mx) + __expf(o1 - mx));
        out[b * 2 + 0] = o0 - mx - ls;
        out[b * 2 + 1] = o1 - mx - ls;
    }
}

extern "C" void kernel_launch(void* const* d_in, const int* in_sizes, int n_in,
                              void* d_out, int out_size, void* d_ws, size_t ws_size,
                              hipStream_t stream) {
    const float* h   = (const float*)d_in[0];
    const int*   adj = (const int*)d_in[1];
    const float* W1  = (const float*)d_in[2];
    const float* b1  = (const float*)d_in[3];
    const float* Wg  = (const float*)d_in[4];
    const float* bg  = (const float*)d_in[5];
    const float* a1  = (const float*)d_in[6];
    const float* a2  = (const float*)d_in[7];
    const float* W2  = (const float*)d_in[8];
    const float* b2  = (const float*)d_in[9];
    float* out = (float*)d_out;

    float* Wh  = (float*)d_ws;                 // B*N*D
    float* e1g = Wh + (size_t)B * N * D;       // B*N
    float* e2g = e1g + (size_t)B * N;          // B*N
    unsigned* pooled = (unsigned*)(e2g + (size_t)B * N);  // B*D

    hipMemsetAsync(pooled, 0, B * D * sizeof(unsigned), stream);

    k_proj<<<(B * N) / TR, 256, 0, stream>>>(h, W1, b1, Wg, bg, a1, a2, Wh, e1g, e2g);
    k_attn<<<dim3(N / TI, B), 256, 0, stream>>>(adj, Wh, e1g, e2g, pooled);
    k_final<<<1, 256, 0, stream>>>(pooled, W2, b2, out);
}

// Round 2
// 252.815 us; speedup vs baseline: 1.8936x; 1.8936x over previous
//
#include <hip/hip_runtime.h>

#define B 8
#define N 2048
#define FIN 10
#define D 128
#define ALPHA 0.02f
#define BR 32     // rows per block, k_proj
#define TI 32     // rows per block, k_attn
#define JC 128    // j-chunk, k_attn

typedef short bf8 __attribute__((ext_vector_type(8)));   // 8 bf16 in 4 VGPRs
typedef short s4v __attribute__((ext_vector_type(4)));
typedef float f32x4 __attribute__((ext_vector_type(4)));

__device__ __forceinline__ float lrelu(float x) { return x >= 0.f ? x : ALPHA * x; }

// f32 -> bf16 (RNE) and back
__device__ __forceinline__ short f2b(float f) {
    unsigned u = __float_as_uint(f);
    return (short)((u + 0x7fffu + ((u >> 16) & 1u)) >> 16);
}
__device__ __forceinline__ float b2f(short s) {
    return __uint_as_float(((unsigned)(unsigned short)s) << 16);
}

// monotone float<->uint encoding for atomicMax pooling
__device__ __forceinline__ unsigned enc_key(float v) {
    unsigned b = __float_as_uint(v);
    return (b & 0x80000000u) ? ~b : (b | 0x80000000u);
}
__device__ __forceinline__ float dec_key(unsigned k) {
    unsigned b = (k & 0x80000000u) ? (k & 0x7fffffffu) : ~k;
    return __uint_as_float(b);
}

// ---------------------------------------------------------------------------
// k_proj: x = lrelu(LN(h@W1^T+b1)) [bf16] ; Wh = x@Wg^T+bg via MFMA (fp32 acc);
// emits WhT bf16 [d][j] (per batch) + e1,e2 fp32.
// Block = 32 rows, 256 threads (4 waves). Grid = B*N/32 = 512.
// ---------------------------------------------------------------------------
__global__ __launch_bounds__(256) void k_proj(
    const float* __restrict__ h, const float* __restrict__ W1, const float* __restrict__ b1,
    const float* __restrict__ Wg, const float* __restrict__ bg,
    const float* __restrict__ a1, const float* __restrict__ a2,
    unsigned short* __restrict__ WhT, float* __restrict__ e1g, float* __restrict__ e2g)
{
    // xep: phase2 A-operand x[32][136] (8704 shorts is max vs ep 128*36=4608)
    __shared__ __align__(16) short xep_lds[32 * 136];
    __shared__ __align__(16) short wg_lds[D * 136];      // B-op: [n=dout][k=din], pad 8
    __shared__ float W1_lds[D * 11];                     // pad 10 -> 11
    __shared__ float h_lds[BR * FIN];
    __shared__ float ep1[2][BR], ep2[2][BR];

    const int t = threadIdx.x;
    const int r0 = blockIdx.x * BR;          // global row over B*N
    const int bb = r0 >> 11;                 // batch
    const int jloc = r0 & (N - 1);           // row base within batch

    for (int idx = t; idx < D * FIN; idx += 256)
        W1_lds[(idx / FIN) * 11 + (idx % FIN)] = W1[idx];
    for (int idx = t; idx < BR * FIN; idx += 256)
        h_lds[idx] = h[(size_t)r0 * FIN + idx];
    __syncthreads();

    // stage Wg -> bf16 LDS [dout][din] (coalesced 512B rows)
    {
        const int dr = t >> 4;               // 0..15
        const int j8 = t & 15;
        #pragma unroll
        for (int pass = 0; pass < 8; pass++) {
            int dd = pass * 16 + dr;
            float4 f0 = *(const float4*)&Wg[dd * D + j8 * 8];
            float4 f1 = *(const float4*)&Wg[dd * D + j8 * 8 + 4];
            bf8 v;
            v[0] = f2b(f0.x); v[1] = f2b(f0.y); v[2] = f2b(f0.z); v[3] = f2b(f0.w);
            v[4] = f2b(f1.x); v[5] = f2b(f1.y); v[6] = f2b(f1.z); v[7] = f2b(f1.w);
            *(bf8*)&wg_lds[dd * 136 + j8 * 8] = v;
        }
    }

    // phase 1: fc1 + LN + lrelu, one row per wave iteration (no barriers)
    const int w = t >> 6, lane = t & 63;
    {
        float b1v0 = b1[lane], b1v1 = b1[lane + 64];
        for (int i = 0; i < 8; i++) {
            int r = w * 8 + i;
            float s0 = b1v0, s1 = b1v1;
            const float* hr = &h_lds[r * FIN];
            #pragma unroll
            for (int k = 0; k < FIN; k++) {
                float hv = hr[k];
                s0 += hv * W1_lds[lane * 11 + k];
                s1 += hv * W1_lds[(lane + 64) * 11 + k];
            }
            float sm = s0 + s1, sq = s0 * s0 + s1 * s1;
            #pragma unroll
            for (int m = 1; m <= 32; m <<= 1) { sm += __shfl_xor(sm, m); sq += __shfl_xor(sq, m); }
            float mean = sm * (1.f / D);
            float var  = sq * (1.f / D) - mean * mean;
            float rs = rsqrtf(var + 1e-5f);
            xep_lds[r * 136 + lane]      = f2b(lrelu((s0 - mean) * rs));
            xep_lds[r * 136 + lane + 64] = f2b(lrelu((s1 - mean) * rs));
        }
    }
    __syncthreads();

    // phase 2: MFMA  Wh[32][128] = x @ Wg^T
    const int l15 = lane & 15, q = lane >> 4;
    const int mw = w & 1, np = w >> 1;
    f32x4 acc[4];
    #pragma unroll
    for (int nt = 0; nt < 4; nt++)
        #pragma unroll
        for (int r = 0; r < 4; r++) acc[nt][r] = 0.f;

    #pragma unroll
    for (int ks = 0; ks < 4; ks++) {
        bf8 av = *(const bf8*)&xep_lds[(mw * 16 + l15) * 136 + ks * 32 + q * 8];
        #pragma unroll
        for (int nt = 0; nt < 4; nt++) {
            bf8 bv = *(const bf8*)&wg_lds[((np * 4 + nt) * 16 + l15) * 136 + ks * 32 + q * 8];
            acc[nt] = __builtin_amdgcn_mfma_f32_16x16x32_bf16(av, bv, acc[nt], 0, 0, 0);
        }
    }

    // epilogue: +bg, e1/e2 partials
    float e1p[4] = {0.f, 0.f, 0.f, 0.f}, e2p[4] = {0.f, 0.f, 0.f, 0.f};
    #pragma unroll
    for (int nt = 0; nt < 4; nt++) {
        int col = (np * 4 + nt) * 16 + l15;
        float bgv = bg[col], a1v = a1[col], a2v = a2[col];
        #pragma unroll
        for (int r = 0; r < 4; r++) {
            float v = acc[nt][r] + bgv;
            acc[nt][r] = v;
            e1p[r] += v * a1v;
            e2p[r] += v * a2v;
        }
    }
    #pragma unroll
    for (int m = 1; m <= 8; m <<= 1) {
        #pragma unroll
        for (int r = 0; r < 4; r++) { e1p[r] += __shfl_xor(e1p[r], m); e2p[r] += __shfl_xor(e2p[r], m); }
    }
    if (l15 == 0) {
        #pragma unroll
        for (int r = 0; r < 4; r++) {
            ep1[np][mw * 16 + q * 4 + r] = e1p[r];
            ep2[np][mw * 16 + q * 4 + r] = e2p[r];
        }
    }
    __syncthreads();   // ep ready; all MFMA A-reads of xep done
    if (t < BR) {
        e1g[r0 + t] = ep1[0][t] + ep1[1][t];
        e2g[r0 + t] = ep2[0][t] + ep2[1][t];
    }
    // write Wh^T bf16 into xep (reused as [col=128][j=32 pad->36])
    #pragma unroll
    for (int nt = 0; nt < 4; nt++) {
        int col = (np * 4 + nt) * 16 + l15;
        #pragma unroll
        for (int r = 0; r < 4; r++)
            xep_lds[col * 36 + mw * 16 + q * 4 + r] = f2b(acc[nt][r]);
    }
    __syncthreads();
    // coalesced global store of WhT slice [128][32]
    {
        const int col = t >> 1, jh = (t & 1) * 16;
        unsigned short* dst = WhT + ((size_t)(bb * D + col)) * N + jloc + jh;
        #pragma unroll
        for (int i2 = 0; i2 < 4; i2++)
            *(uint2*)(dst + i2 * 4) = *(const uint2*)&xep_lds[col * 36 + jh + i2 * 4];
    }
}

// ---------------------------------------------------------------------------
// k_attn: flash-style GAT attention with MFMA PV.
// Block = 32 i-rows, 256 threads (4 waves). Grid (N/32, B) = 512.
// ---------------------------------------------------------------------------
__global__ __launch_bounds__(256) void k_attn(
    const int* __restrict__ adj, const unsigned short* __restrict__ WhT,
    const float* __restrict__ e1g, const float* __restrict__ e2g,
    unsigned* __restrict__ pooled)
{
    __shared__ __align__(16) short pT[TI * 136];     // A-op: [i][j], pad 8
    __shared__ __align__(16) short whT[D * 136];     // B-op: [d][j], pad 8
    __shared__ float e1_lds[TI];
    __shared__ float l_lds[TI];
    __shared__ float statsp[2][TI][2];
    __shared__ float maxb[2][D];

    const int t = threadIdx.x;
    const int b = blockIdx.y;
    const int i0 = blockIdx.x * TI;

    if (t < TI) { e1_lds[t] = e1g[b * N + i0 + t]; l_lds[t] = 0.f; }

    const int w = t >> 6, lane = t & 63;
    const int l15 = lane & 15, q = lane >> 4;
    const int mw = w & 1, np = w >> 1;

    // staging maps
    const int dr = t >> 4, j8 = t & 15;              // whT staging
    const int jq = (t & 31) * 4, rg = t >> 5;        // pT staging: 4 rows x 4 j

    const unsigned short* WhTb = WhT + (size_t)b * D * N;

    f32x4 acc[4];
    #pragma unroll
    for (int nt = 0; nt < 4; nt++)
        #pragma unroll
        for (int r = 0; r < 4; r++) acc[nt][r] = 0.f;

    for (int jc = 0; jc < N / JC; jc++) {
        const int j0 = jc * JC;
        __syncthreads();   // prev chunk MFMA reads done; (iter0: e1/l init visible)

        // stage whT slice (straight bf16 copy, coalesced)
        #pragma unroll
        for (int pass = 0; pass < 8; pass++) {
            int dd = pass * 16 + dr;
            *(bf8*)&whT[dd * 136 + j8 * 8] = *(const bf8*)(WhTb + (size_t)dd * N + j0 + j8 * 8);
        }
        // stage pT + accumulate l (consistent with bf16-rounded p)
        {
            float4 e2v4 = *(const float4*)&e2g[b * N + j0 + jq];
            const int* ap = adj + ((size_t)b * N + i0 + rg * 4) * N + j0 + jq;
            #pragma unroll
            for (int rr = 0; rr < 4; rr++) {
                int ii = rg * 4 + rr;
                int4 a4 = *(const int4*)(ap + rr * N);
                float e1v = e1_lds[ii];
                short p0 = f2b(a4.x ? __expf(lrelu(e1v + e2v4.x)) : 0.f);
                short p1 = f2b(a4.y ? __expf(lrelu(e1v + e2v4.y)) : 0.f);
                short p2 = f2b(a4.z ? __expf(lrelu(e1v + e2v4.z)) : 0.f);
                short p3 = f2b(a4.w ? __expf(lrelu(e1v + e2v4.w)) : 0.f);
                s4v pv; pv[0] = p0; pv[1] = p1; pv[2] = p2; pv[3] = p3;
                *(s4v*)&pT[ii * 136 + jq] = pv;
                float sr = b2f(p0) + b2f(p1) + b2f(p2) + b2f(p3);
                #pragma unroll
                for (int m = 1; m <= 16; m <<= 1) sr += __shfl_xor(sr, m);
                if ((t & 31) == 0) l_lds[ii] += sr;
            }
        }
        __syncthreads();

        // MFMA: O[32][128] += P[32][128-chunk] @ WhT^T
        #pragma unroll
        for (int ks = 0; ks < 4; ks++) {
            bf8 av = *(const bf8*)&pT[(mw * 16 + l15) * 136 + ks * 32 + q * 8];
            #pragma unroll
            for (int nt = 0; nt < 4; nt++) {
                bf8 bv = *(const bf8*)&whT[((np * 4 + nt) * 16 + l15) * 136 + ks * 32 + q * 8];
                acc[nt] = __builtin_amdgcn_mfma_f32_16x16x32_bf16(av, bv, acc[nt], 0, 0, 0);
            }
        }
    }
    __syncthreads();   // all l_lds contributions visible

    // epilogue: /l -> LN stats (cross-np via LDS) -> lrelu -> max-pool
    float lr[4];
    #pragma unroll
    for (int r = 0; r < 4; r++) lr[r] = l_lds[mw * 16 + q * 4 + r];

    float smr[4] = {0.f, 0.f, 0.f, 0.f}, sqr[4] = {0.f, 0.f, 0.f, 0.f};
    #pragma unroll
    for (int nt = 0; nt < 4; nt++)
        #pragma unroll
        for (int r = 0; r < 4; r++) {
            float v = acc[nt][r] / lr[r];
            acc[nt][r] = v;
            smr[r] += v;
            sqr[r] += v * v;
        }
    #pragma unroll
    for (int m = 1; m <= 8; m <<= 1) {
        #pragma unroll
        for (int r = 0; r < 4; r++) { smr[r] += __shfl_xor(smr[r], m); sqr[r] += __shfl_xor(sqr[r], m); }
    }
    if (l15 == 0) {
        #pragma unroll
        for (int r = 0; r < 4; r++) {
            statsp[np][mw * 16 + q * 4 + r][0] = smr[r];
            statsp[np][mw * 16 + q * 4 + r][1] = sqr[r];
        }
    }
    __syncthreads();

    float mx[4] = {-1e30f, -1e30f, -1e30f, -1e30f};
    #pragma unroll
    for (int r = 0; r < 4; r++) {
        int row = mw * 16 + q * 4 + r;
        float s0 = statsp[0][row][0] + statsp[1][row][0];
        float s1 = statsp[0][row][1] + statsp[1][row][1];
        float mean = s0 * (1.f / D);
        float var  = s1 * (1.f / D) - mean * mean;
        float rs = rsqrtf(var + 1e-5f);
        #pragma unroll
        for (int nt = 0; nt < 4; nt++) {
            float v = lrelu((acc[nt][r] - mean) * rs);
            mx[nt] = fmaxf(mx[nt], v);
        }
    }
    #pragma unroll
    for (int m = 16; m <= 32; m <<= 1) {
        #pragma unroll
        for (int nt = 0; nt < 4; nt++) mx[nt] = fmaxf(mx[nt], __shfl_xor(mx[nt], m));
    }
    if (q == 0) {
        #pragma unroll
        for (int nt = 0; nt < 4; nt++) maxb[mw][np * 64 + nt * 16 + l15] = mx[nt];
    }
    __syncthreads();
    if (t < D) {
        float v = fmaxf(maxb[0][t], maxb[1][t]);
        atomicMax(&pooled[b * D + t], enc_key(v));
    }
}

// ---------------------------------------------------------------------------
// k_final: out = log_softmax(pooled @ W2^T + b2)
// ---------------------------------------------------------------------------
__global__ __launch_bounds__(256) void k_final(
    const unsigned* __restrict__ pooled, const float* __restrict__ W2,
    const float* __restrict__ b2, float* __restrict__ out)
{
    const int t = threadIdx.x;
    const int b = t >> 5;
    const int q = t & 31;
    float s0 = 0.f, s1 = 0.f;
    #pragma unroll
    for (int m = 0; m < 4; m++) {
        int dd = q + 32 * m;
        float v = dec_key(pooled[b * D + dd]);
        s0 += v * W2[dd];
        s1 += v * W2[D + dd];
    }
    #pragma unroll
    for (int m = 1; m <= 16; m <<= 1) { s0 += __shfl_xor(s0, m); s1 += __shfl_xor(s1, m); }
    if (q == 0) {
        float o0 = s0 + b2[0], o1 = s1 + b2[1];
        float mxv = fmaxf(o0, o1);
        float ls = logf(__expf(o0 - mxv) + __expf(o1 - mxv));
        out[b * 2 + 0] = o0 - mxv - ls;
        out[b * 2 + 1] = o1 - mxv - ls;
    }
}

extern "C" void kernel_launch(void* const* d_in, const int* in_sizes, int n_in,
                              void* d_out, int out_size, void* d_ws, size_t ws_size,
                              hipStream_t stream) {
    const float* h   = (const float*)d_in[0];
    const int*   adj = (const int*)d_in[1];
    const float* W1  = (const float*)d_in[2];
    const float* b1  = (const float*)d_in[3];
    const float* Wg  = (const float*)d_in[4];
    const float* bg  = (const float*)d_in[5];
    const float* a1  = (const float*)d_in[6];
    const float* a2  = (const float*)d_in[7];
    const float* W2  = (const float*)d_in[8];
    const float* b2  = (const float*)d_in[9];
    float* out = (float*)d_out;

    unsigned short* WhT = (unsigned short*)d_ws;                       // B*D*N bf16
    float* e1g = (float*)((char*)d_ws + (size_t)B * D * N * 2);        // B*N f32
    float* e2g = e1g + (size_t)B * N;                                  // B*N f32
    unsigned* pooled = (unsigned*)(e2g + (size_t)B * N);               // B*D u32

    hipMemsetAsync(pooled, 0, B * D * sizeof(unsigned), stream);

    k_proj<<<(B * N) / BR, 256, 0, stream>>>(h, W1, b1, Wg, bg, a1, a2, WhT, e1g, e2g);
    k_attn<<<dim3(N / TI, B), 256, 0, stream>>>(adj, WhT, e1g, e2g, pooled);
    k_final<<<1, 256, 0, stream>>>(pooled, W2, b2, out);
}

// Round 3
// 238.432 us; speedup vs baseline: 2.0078x; 1.0603x over previous
//
#include <hip/hip_runtime.h>

#define B 8
#define N 2048
#define FIN 10
#define D 128
#define ALPHA 0.02f
#define BR 32     // rows per block, k_proj
#define TI 32     // rows per block, k_attn
#define JC 128    // j-chunk, k_attn
#define NBLK_ATTN ((N / TI) * B)   // 512

typedef short bf8 __attribute__((ext_vector_type(8)));   // 8 bf16 in 4 VGPRs
typedef short s4v __attribute__((ext_vector_type(4)));
typedef float f32x4 __attribute__((ext_vector_type(4)));

__device__ __forceinline__ float lrelu(float x) { return x >= 0.f ? x : ALPHA * x; }

__device__ __forceinline__ short f2b(float f) {
    unsigned u = __float_as_uint(f);
    return (short)((u + 0x7fffu + ((u >> 16) & 1u)) >> 16);
}

__device__ __forceinline__ unsigned enc_key(float v) {
    unsigned b = __float_as_uint(v);
    return (b & 0x80000000u) ? ~b : (b | 0x80000000u);
}
__device__ __forceinline__ float dec_key(unsigned k) {
    unsigned b = (k & 0x80000000u) ? (k & 0x7fffffffu) : ~k;
    return __uint_as_float(b);
}

// ---------------------------------------------------------------------------
// k_proj: x = lrelu(LN(h@W1^T+b1)) [bf16] ; Wh = x@Wg^T+bg via MFMA (fp32 acc);
// emits WhT bf16 [d][j] + e1,e2 fp32. Also zero-inits pooled + completion cnt.
// Block = 32 rows, 256 threads (4 waves). Grid = B*N/32 = 512.
// ---------------------------------------------------------------------------
__global__ __launch_bounds__(256) void k_proj(
    const float* __restrict__ h, const float* __restrict__ W1, const float* __restrict__ b1,
    const float* __restrict__ Wg, const float* __restrict__ bg,
    const float* __restrict__ a1, const float* __restrict__ a2,
    unsigned short* __restrict__ WhT, float* __restrict__ e1g, float* __restrict__ e2g,
    unsigned* __restrict__ pooled, unsigned* __restrict__ cnt)
{
    __shared__ __align__(16) short xep_lds[32 * 136];
    __shared__ __align__(16) short wg_lds[D * 136];
    __shared__ float W1_lds[D * 11];
    __shared__ float h_lds[BR * FIN];
    __shared__ float ep1[2][BR], ep2[2][BR];

    const int t = threadIdx.x;
    const int r0 = blockIdx.x * BR;
    const int bb = r0 >> 11;
    const int jloc = r0 & (N - 1);

    // zero-init pooled (blocks 0..7) and counter (block 0)
    if (blockIdx.x < B && t < D) pooled[blockIdx.x * D + t] = 0u;
    if (blockIdx.x == 0 && t == 128) *cnt = 0u;

    for (int idx = t; idx < D * FIN; idx += 256)
        W1_lds[(idx / FIN) * 11 + (idx % FIN)] = W1[idx];
    for (int idx = t; idx < BR * FIN; idx += 256)
        h_lds[idx] = h[(size_t)r0 * FIN + idx];
    __syncthreads();

    // stage Wg -> bf16 LDS [dout][din]
    {
        const int dr = t >> 4;
        const int j8 = t & 15;
        #pragma unroll
        for (int pass = 0; pass < 8; pass++) {
            int dd = pass * 16 + dr;
            float4 f0 = *(const float4*)&Wg[dd * D + j8 * 8];
            float4 f1 = *(const float4*)&Wg[dd * D + j8 * 8 + 4];
            bf8 v;
            v[0] = f2b(f0.x); v[1] = f2b(f0.y); v[2] = f2b(f0.z); v[3] = f2b(f0.w);
            v[4] = f2b(f1.x); v[5] = f2b(f1.y); v[6] = f2b(f1.z); v[7] = f2b(f1.w);
            *(bf8*)&wg_lds[dd * 136 + j8 * 8] = v;
        }
    }

    // phase 1: fc1 + LN + lrelu, one row per wave iteration
    const int w = t >> 6, lane = t & 63;
    {
        float b1v0 = b1[lane], b1v1 = b1[lane + 64];
        for (int i = 0; i < 8; i++) {
            int r = w * 8 + i;
            float s0 = b1v0, s1 = b1v1;
            const float* hr = &h_lds[r * FIN];
            #pragma unroll
            for (int k = 0; k < FIN; k++) {
                float hv = hr[k];
                s0 += hv * W1_lds[lane * 11 + k];
                s1 += hv * W1_lds[(lane + 64) * 11 + k];
            }
            float sm = s0 + s1, sq = s0 * s0 + s1 * s1;
            #pragma unroll
            for (int m = 1; m <= 32; m <<= 1) { sm += __shfl_xor(sm, m); sq += __shfl_xor(sq, m); }
            float mean = sm * (1.f / D);
            float var  = sq * (1.f / D) - mean * mean;
            float rs = rsqrtf(var + 1e-5f);
            xep_lds[r * 136 + lane]      = f2b(lrelu((s0 - mean) * rs));
            xep_lds[r * 136 + lane + 64] = f2b(lrelu((s1 - mean) * rs));
        }
    }
    __syncthreads();

    // phase 2: MFMA  Wh[32][128] = x @ Wg^T
    const int l15 = lane & 15, q = lane >> 4;
    const int mw = w & 1, np = w >> 1;
    f32x4 acc[4];
    #pragma unroll
    for (int nt = 0; nt < 4; nt++)
        #pragma unroll
        for (int r = 0; r < 4; r++) acc[nt][r] = 0.f;

    #pragma unroll
    for (int ks = 0; ks < 4; ks++) {
        bf8 av = *(const bf8*)&xep_lds[(mw * 16 + l15) * 136 + ks * 32 + q * 8];
        #pragma unroll
        for (int nt = 0; nt < 4; nt++) {
            bf8 bv = *(const bf8*)&wg_lds[((np * 4 + nt) * 16 + l15) * 136 + ks * 32 + q * 8];
            acc[nt] = __builtin_amdgcn_mfma_f32_16x16x32_bf16(av, bv, acc[nt], 0, 0, 0);
        }
    }

    // epilogue: +bg, e1/e2 partials
    float e1p[4] = {0.f, 0.f, 0.f, 0.f}, e2p[4] = {0.f, 0.f, 0.f, 0.f};
    #pragma unroll
    for (int nt = 0; nt < 4; nt++) {
        int col = (np * 4 + nt) * 16 + l15;
        float bgv = bg[col], a1v = a1[col], a2v = a2[col];
        #pragma unroll
        for (int r = 0; r < 4; r++) {
            float v = acc[nt][r] + bgv;
            acc[nt][r] = v;
            e1p[r] += v * a1v;
            e2p[r] += v * a2v;
        }
    }
    #pragma unroll
    for (int m = 1; m <= 8; m <<= 1) {
        #pragma unroll
        for (int r = 0; r < 4; r++) { e1p[r] += __shfl_xor(e1p[r], m); e2p[r] += __shfl_xor(e2p[r], m); }
    }
    if (l15 == 0) {
        #pragma unroll
        for (int r = 0; r < 4; r++) {
            ep1[np][mw * 16 + q * 4 + r] = e1p[r];
            ep2[np][mw * 16 + q * 4 + r] = e2p[r];
        }
    }
    __syncthreads();
    if (t < BR) {
        e1g[r0 + t] = ep1[0][t] + ep1[1][t];
        e2g[r0 + t] = ep2[0][t] + ep2[1][t];
    }
    #pragma unroll
    for (int nt = 0; nt < 4; nt++) {
        int col = (np * 4 + nt) * 16 + l15;
        #pragma unroll
        for (int r = 0; r < 4; r++)
            xep_lds[col * 36 + mw * 16 + q * 4 + r] = f2b(acc[nt][r]);
    }
    __syncthreads();
    {
        const int col = t >> 1, jh = (t & 1) * 16;
        unsigned short* dst = WhT + ((size_t)(bb * D + col)) * N + jloc + jh;
        #pragma unroll
        for (int i2 = 0; i2 < 4; i2++)
            *(uint2*)(dst + i2 * 4) = *(const uint2*)&xep_lds[col * 36 + jh + i2 * 4];
    }
}

// ---------------------------------------------------------------------------
// k_attn: flash-style GAT attention, MFMA PV + ones-MFMA for l, register
// prefetch pipeline. Block = 32 i-rows, 512 threads (8 waves). Grid = 512.
// Last block (device counter) computes final log_softmax.
// ---------------------------------------------------------------------------
__global__ __launch_bounds__(512) void k_attn(
    const int* __restrict__ adj, const unsigned short* __restrict__ WhT,
    const float* __restrict__ e1g, const float* __restrict__ e2g,
    unsigned* __restrict__ pooled, unsigned* __restrict__ cnt,
    const float* __restrict__ W2, const float* __restrict__ b2,
    float* __restrict__ out)
{
    __shared__ __align__(16) short pT[TI * 136];     // A-op: [i][k=j], pad 8
    __shared__ __align__(16) short whT[D * 136];     // B-op: [d][k=j], pad 8
    __shared__ float statsp[4][TI][2];
    __shared__ float maxb[2][D];
    __shared__ int finalflag;

    const int t = threadIdx.x;
    const int b = blockIdx.y;
    const int i0 = blockIdx.x * TI;

    const int w = t >> 6, lane = t & 63;
    const int l15 = lane & 15, q = lane >> 4;
    const int mw = w & 1;          // m-tile (0/1)
    const int np = w >> 1;         // n-quarter (0..3), covers cols [np*32, np*32+32)

    // staging maps
    const int rg = t >> 5;                 // 0..15 -> rows {2rg, 2rg+1}
    const int jq = (t & 31) * 4;           // j offset within chunk (int4 granule)
    const int dr = t >> 4;                 // 0..31 (whT rows per pass)
    const int j8 = t & 15;                 // 16B granule within chunk

    const float e1r0 = e1g[b * N + i0 + rg * 2];
    const float e1r1 = e1g[b * N + i0 + rg * 2 + 1];

    const unsigned short* WhTb = WhT + (size_t)b * D * N;
    const int* adjb = adj + ((size_t)b * N + i0) * N;

    f32x4 acc[2], accl;
    #pragma unroll
    for (int nt = 0; nt < 2; nt++)
        #pragma unroll
        for (int r = 0; r < 4; r++) acc[nt][r] = 0.f;
    #pragma unroll
    for (int r = 0; r < 4; r++) accl[r] = 0.f;

    bf8 ones;
    #pragma unroll
    for (int i = 0; i < 8; i++) ones[i] = (short)0x3F80;   // bf16(1.0)

    // prefetch chunk 0
    int4 a0 = *(const int4*)(adjb + (size_t)(rg * 2) * N + jq);
    int4 a1r = *(const int4*)(adjb + (size_t)(rg * 2 + 1) * N + jq);
    float4 e2r = *(const float4*)&e2g[b * N + jq];
    bf8 wr0 = *(const bf8*)(WhTb + (size_t)(0 * 32 + dr) * N + j8 * 8);
    bf8 wr1 = *(const bf8*)(WhTb + (size_t)(1 * 32 + dr) * N + j8 * 8);
    bf8 wr2 = *(const bf8*)(WhTb + (size_t)(2 * 32 + dr) * N + j8 * 8);
    bf8 wr3 = *(const bf8*)(WhTb + (size_t)(3 * 32 + dr) * N + j8 * 8);

    for (int jc = 0; jc < N / JC; jc++) {
        // phase A: LDS writes from prefetched registers (no global latency)
        {
            s4v pv;
            pv[0] = f2b(a0.x ? __expf(lrelu(e1r0 + e2r.x)) : 0.f);
            pv[1] = f2b(a0.y ? __expf(lrelu(e1r0 + e2r.y)) : 0.f);
            pv[2] = f2b(a0.z ? __expf(lrelu(e1r0 + e2r.z)) : 0.f);
            pv[3] = f2b(a0.w ? __expf(lrelu(e1r0 + e2r.w)) : 0.f);
            *(s4v*)&pT[(rg * 2) * 136 + jq] = pv;
            pv[0] = f2b(a1r.x ? __expf(lrelu(e1r1 + e2r.x)) : 0.f);
            pv[1] = f2b(a1r.y ? __expf(lrelu(e1r1 + e2r.y)) : 0.f);
            pv[2] = f2b(a1r.z ? __expf(lrelu(e1r1 + e2r.z)) : 0.f);
            pv[3] = f2b(a1r.w ? __expf(lrelu(e1r1 + e2r.w)) : 0.f);
            *(s4v*)&pT[(rg * 2 + 1) * 136 + jq] = pv;
            *(bf8*)&whT[(0 * 32 + dr) * 136 + j8 * 8] = wr0;
            *(bf8*)&whT[(1 * 32 + dr) * 136 + j8 * 8] = wr1;
            *(bf8*)&whT[(2 * 32 + dr) * 136 + j8 * 8] = wr2;
            *(bf8*)&whT[(3 * 32 + dr) * 136 + j8 * 8] = wr3;
        }
        __syncthreads();

        // phase B: issue next chunk's prefetch (hidden behind MFMA + barrier)
        if (jc < N / JC - 1) {
            const int j0n = (jc + 1) * JC;
            a0  = *(const int4*)(adjb + (size_t)(rg * 2) * N + j0n + jq);
            a1r = *(const int4*)(adjb + (size_t)(rg * 2 + 1) * N + j0n + jq);
            e2r = *(const float4*)&e2g[b * N + j0n + jq];
            wr0 = *(const bf8*)(WhTb + (size_t)(0 * 32 + dr) * N + j0n + j8 * 8);
            wr1 = *(const bf8*)(WhTb + (size_t)(1 * 32 + dr) * N + j0n + j8 * 8);
            wr2 = *(const bf8*)(WhTb + (size_t)(2 * 32 + dr) * N + j0n + j8 * 8);
            wr3 = *(const bf8*)(WhTb + (size_t)(3 * 32 + dr) * N + j0n + j8 * 8);
        }

        // MFMA: O[32][128] += P @ WhT^T ; l += P @ ones
        #pragma unroll
        for (int ks = 0; ks < 4; ks++) {
            bf8 av = *(const bf8*)&pT[(mw * 16 + l15) * 136 + ks * 32 + q * 8];
            #pragma unroll
            for (int nt = 0; nt < 2; nt++) {
                bf8 bv = *(const bf8*)&whT[((np * 2 + nt) * 16 + l15) * 136 + ks * 32 + q * 8];
                acc[nt] = __builtin_amdgcn_mfma_f32_16x16x32_bf16(av, bv, acc[nt], 0, 0, 0);
            }
            accl = __builtin_amdgcn_mfma_f32_16x16x32_bf16(av, ones, accl, 0, 0, 0);
        }
        __syncthreads();
    }

    // epilogue: /l -> LN stats (cross-np via LDS) -> lrelu -> max-pool
    float smr[4] = {0.f, 0.f, 0.f, 0.f}, sqr[4] = {0.f, 0.f, 0.f, 0.f};
    #pragma unroll
    for (int r = 0; r < 4; r++) {
        float rinv = 1.f / accl[r];
        #pragma unroll
        for (int nt = 0; nt < 2; nt++) {
            float v = acc[nt][r] * rinv;
            acc[nt][r] = v;
            smr[r] += v;
            sqr[r] += v * v;
        }
    }
    #pragma unroll
    for (int m = 1; m <= 8; m <<= 1) {
        #pragma unroll
        for (int r = 0; r < 4; r++) { smr[r] += __shfl_xor(smr[r], m); sqr[r] += __shfl_xor(sqr[r], m); }
    }
    if (l15 == 0) {
        #pragma unroll
        for (int r = 0; r < 4; r++) {
            statsp[np][mw * 16 + q * 4 + r][0] = smr[r];
            statsp[np][mw * 16 + q * 4 + r][1] = sqr[r];
        }
    }
    __syncthreads();

    float mx[2] = {-1e30f, -1e30f};
    #pragma unroll
    for (int r = 0; r < 4; r++) {
        int row = mw * 16 + q * 4 + r;
        float s0 = statsp[0][row][0] + statsp[1][row][0] + statsp[2][row][0] + statsp[3][row][0];
        float s1 = statsp[0][row][1] + statsp[1][row][1] + statsp[2][row][1] + statsp[3][row][1];
        float mean = s0 * (1.f / D);
        float var  = s1 * (1.f / D) - mean * mean;
        float rs = rsqrtf(var + 1e-5f);
        #pragma unroll
        for (int nt = 0; nt < 2; nt++) {
            float v = lrelu((acc[nt][r] - mean) * rs);
            mx[nt] = fmaxf(mx[nt], v);
        }
    }
    #pragma unroll
    for (int m = 16; m <= 32; m <<= 1) {
        #pragma unroll
        for (int nt = 0; nt < 2; nt++) mx[nt] = fmaxf(mx[nt], __shfl_xor(mx[nt], m));
    }
    if (q == 0) {
        #pragma unroll
        for (int nt = 0; nt < 2; nt++) maxb[mw][(np * 2 + nt) * 16 + l15] = mx[nt];
    }
    __syncthreads();
    if (t < D) {
        float v = fmaxf(maxb[0][t], maxb[1][t]);
        atomicMax(&pooled[b * D + t], enc_key(v));
    }
    __syncthreads();           // all this block's atomics drained

    // completion counter; last block does final 128->2 matmul + log_softmax
    if (t == 0) {
        __threadfence();
        unsigned old = atomicAdd(cnt, 1u);
        finalflag = (old == NBLK_ATTN - 1) ? 1 : 0;
    }
    __syncthreads();
    if (finalflag && t < 256) {
        const int fb = t >> 5;
        const int fq = t & 31;
        float s0 = 0.f, s1 = 0.f;
        #pragma unroll
        for (int m = 0; m < 4; m++) {
            int dd = fq + 32 * m;
            unsigned key = __hip_atomic_load(&pooled[fb * D + dd], __ATOMIC_RELAXED,
                                             __HIP_MEMORY_SCOPE_AGENT);
            float v = dec_key(key);
            s0 += v * W2[dd];
            s1 += v * W2[D + dd];
        }
        #pragma unroll
        for (int m = 1; m <= 16; m <<= 1) { s0 += __shfl_xor(s0, m); s1 += __shfl_xor(s1, m); }
        if (fq == 0) {
            float o0 = s0 + b2[0], o1 = s1 + b2[1];
            float mxv = fmaxf(o0, o1);
            float ls = logf(__expf(o0 - mxv) + __expf(o1 - mxv));
            out[fb * 2 + 0] = o0 - mxv - ls;
            out[fb * 2 + 1] = o1 - mxv - ls;
        }
    }
}

extern "C" void kernel_launch(void* const* d_in, const int* in_sizes, int n_in,
                              void* d_out, int out_size, void* d_ws, size_t ws_size,
                              hipStream_t stream) {
    const float* h   = (const float*)d_in[0];
    const int*   adj = (const int*)d_in[1];
    const float* W1  = (const float*)d_in[2];
    const float* b1  = (const float*)d_in[3];
    const float* Wg  = (const float*)d_in[4];
    const float* bg  = (const float*)d_in[5];
    const float* a1  = (const float*)d_in[6];
    const float* a2  = (const float*)d_in[7];
    const float* W2  = (const float*)d_in[8];
    const float* b2  = (const float*)d_in[9];
    float* out = (float*)d_out;

    unsigned short* WhT = (unsigned short*)d_ws;                       // B*D*N bf16
    float* e1g = (float*)((char*)d_ws + (size_t)B * D * N * 2);        // B*N f32
    float* e2g = e1g + (size_t)B * N;                                  // B*N f32
    unsigned* pooled = (unsigned*)(e2g + (size_t)B * N);               // B*D u32
    unsigned* cnt = pooled + (size_t)B * D;                            // 1 u32

    k_proj<<<(B * N) / BR, 256, 0, stream>>>(h, W1, b1, Wg, bg, a1, a2,
                                             WhT, e1g, e2g, pooled, cnt);
    k_attn<<<dim3(N / TI, B), 512, 0, stream>>>(adj, WhT, e1g, e2g, pooled, cnt,
                                                W2, b2, out);
}